// Round 18
// baseline (407.873 us; speedup 1.0000x reference)
//
#include <hip/hip_runtime.h>

#define B_ 8
#define N_ 1024
#define C1_ 64
#define C2_ 128
#define K_ 1024
#define EPS_ 1e-5f
#define XTOL_ 1e-7f

// workspace offsets (in floats)
#define OFF_G      0        // 128
#define OFF_F0     128      // 8192
#define OFF_PM     8320     // u64[8192]
#define OFF_M1     24704    // u64[8192]
#define OFF_M2     41088    // u32[8192*4]
#define OFF_SC3    73856    // 1024
#define OFF_OFF3   74880    // 1024
#define OFF_OFF2   75904    // 128
#define OFF_W1F    76032    // 64*4
#define OFF_W3HI   76288    // 1024*128 ushort
#define OFF_W3LO   141824   // 1024*128 ushort
#define OFF_W2H    207360   // 128*64 ushort
#define OFF_W2L    211456   // 128*64 ushort
#define OFF_J      215552   // 8*1024*6
#define OFF_PINVT  264704   // 8*1024*8
#define OFF_PART   330240   // u64[8*8*1024] = 131072 floats
#define OFF_DXG    461312   // 48
#define OFF_NRM    461360   // 8
#define OFF_CNT    461368   // 1 (uint)
// total 461372 floats = 1.85 MB

typedef __attribute__((ext_vector_type(8))) short bf16x8;
typedef __attribute__((ext_vector_type(4))) float f32x4;

static __device__ inline unsigned short f2bf(float x) {
    unsigned u = __float_as_uint(x);
    unsigned r = (u + 0x7FFFu + ((u >> 16) & 1u)) >> 16;
    return (unsigned short)r;
}
static __device__ inline float bf2f(unsigned short h) {
    return __uint_as_float(((unsigned)h) << 16);
}
static __device__ inline unsigned pk2(unsigned short a, unsigned short b) {
    return (unsigned)a | ((unsigned)b << 16);
}

// One-time: split W3/W2 into bf16 hi/lo planes; fold BN into tables; cnt=0.
__global__ __launch_bounds__(256)
void k_prep(const float* __restrict__ W3, const float* __restrict__ b3,
            const float* __restrict__ ga3, const float* __restrict__ be3,
            const float* __restrict__ rm3, const float* __restrict__ rv3,
            const float* __restrict__ W1, const float* __restrict__ b1,
            const float* __restrict__ ga1, const float* __restrict__ be1,
            const float* __restrict__ rm1, const float* __restrict__ rv1,
            const float* __restrict__ W2, const float* __restrict__ b2,
            const float* __restrict__ ga2, const float* __restrict__ be2,
            const float* __restrict__ rm2, const float* __restrict__ rv2,
            unsigned short* __restrict__ w3hi, unsigned short* __restrict__ w3lo,
            float* __restrict__ sc3, float* __restrict__ off3,
            unsigned short* __restrict__ w2h, unsigned short* __restrict__ w2l,
            float* __restrict__ off2, float* __restrict__ w1f,
            unsigned int* __restrict__ cnt) {
    int gid = blockIdx.x * 256 + threadIdx.x;
    if (gid < K_ * C2_) {
        float w = W3[gid];
        unsigned short h = f2bf(w);
        w3hi[gid] = h;
        w3lo[gid] = f2bf(w - bf2f(h));
    }
    if (gid < K_) {
        float sc = ga3[gid] * rsqrtf(rv3[gid] + EPS_);
        sc3[gid] = sc;
        off3[gid] = sc * (b3[gid] - rm3[gid]) + be3[gid];
    }
    if (gid < C2_ * C1_) {
        int o = gid >> 6, c = gid & 63;
        float sc = ga2[o] * rsqrtf(rv2[o] + EPS_);
        float v = W2[o * C1_ + c] * sc;
        unsigned short h = f2bf(v);
        w2h[o * C1_ + c] = h;
        w2l[o * C1_ + c] = f2bf(v - bf2f(h));
    }
    if (gid < C2_) {
        float sc = ga2[gid] * rsqrtf(rv2[gid] + EPS_);
        off2[gid] = sc * (b2[gid] - rm2[gid]) + be2[gid];
    }
    if (gid < C1_) {
        float sc = ga1[gid] * rsqrtf(rv1[gid] + EPS_);
        w1f[gid * 4 + 0] = W1[gid * 3 + 0] * sc;
        w1f[gid * 4 + 1] = W1[gid * 3 + 1] * sc;
        w1f[gid * 4 + 2] = W1[gid * 3 + 2] * sc;
        w1f[gid * 4 + 3] = sc * (b1[gid] - rm1[gid]) + be1[gid];
    }
    if (gid == 0) *cnt = 0u;
}

// Fused PointNet pass. 1024-thr blocks; LDS ~77.5 KB and VGPR<=64
// (launch_bounds(1024,8)) -> 2 blocks/CU, 8 waves/SIMD. Layer2+layer3
// process 128 n in two 64-n halves reusing one sB buffer; layer3 is
// register-minimal (per-nf acc + immediate BN/max).
// MODE 0: q==0 block also emits sign-bitmasks for k_jac.
template<int MODE>
__global__ __launch_bounds__(1024, 8)
void k_fused(const float* __restrict__ pts, const float* __restrict__ g,
             const float* __restrict__ w1f,
             const unsigned short* __restrict__ w2h, const unsigned short* __restrict__ w2l,
             const float* __restrict__ off2,
             const unsigned short* __restrict__ w3hi, const unsigned short* __restrict__ w3lo,
             const float* __restrict__ sc3, const float* __restrict__ off3,
             unsigned long long* __restrict__ part,
             unsigned long long* __restrict__ m1b, unsigned int* __restrict__ m2q) {
    __shared__ __align__(16) unsigned short a1h[128][72];   // 18 KB
    __shared__ __align__(16) unsigned short a1l[128][72];   // 18 KB
    __shared__ __align__(16) unsigned short sB[2][64][136]; // 34 KB (n-half)
    __shared__ float sSc[256], sOff[256], sOff2[C2_];
    __shared__ unsigned int m1w[2][128];
    __shared__ unsigned int m2w[4][128];
    __shared__ unsigned long long pmL[256];

    int slab = blockIdx.x;         // 0..7 (128 pts each)
    int b    = blockIdx.y;         // 0..7
    int q    = blockIdx.z;         // 0..3 (256-o quarter)
    int n0   = slab * 128;
    int tx   = threadIdx.x;        // 0..1023
    int w    = tx >> 6;            // wave 0..15
    int l    = tx & 63;
    int l15  = l & 15;
    int lhi  = l >> 4;

    if (tx < 256) { sSc[tx] = sc3[q * 256 + tx]; sOff[tx] = off3[q * 256 + tx]; }
    if (tx < C2_) sOff2[tx] = off2[tx];
    if (MODE == 0 && tx < 128) {
        m1w[0][tx] = 0u; m1w[1][tx] = 0u;
        m2w[0][tx] = 0u; m2w[1][tx] = 0u; m2w[2][tx] = 0u; m2w[3][tx] = 0u;
    }
    __syncthreads();

    // ---- layer1 (+SE3 in MODE 1): thread (n = tx&127, cg = tx>>7 covers 8 c)
    {
        int n = tx & 127;
        int cgi = tx >> 7;         // 0..7
        const float* pp = pts + (b * N_ + n0 + n) * 3;
        float px = pp[0], py = pp[1], pz = pp[2];
        float q0, q1, q2;
        if (MODE == 1) {
            const float* gb = g + b * 16;
            q0 = fmaf(gb[0], px, fmaf(gb[1], py, fmaf(gb[2],  pz, gb[3])));
            q1 = fmaf(gb[4], px, fmaf(gb[5], py, fmaf(gb[6],  pz, gb[7])));
            q2 = fmaf(gb[8], px, fmaf(gb[9], py, fmaf(gb[10], pz, gb[11])));
        } else {
            q0 = px; q1 = py; q2 = pz;
        }
        unsigned int bits = 0u;
        unsigned hw[4], lw[4];
        #pragma unroll
        for (int j = 0; j < 8; ++j) {
            int c = cgi * 8 + j;
            float4 wf = *(const float4*)(w1f + c * 4);
            float y = fmaxf(fmaf(wf.x, q0, fmaf(wf.y, q1, fmaf(wf.z, q2, wf.w))), 0.f);
            unsigned short h = f2bf(y);
            unsigned short lo = f2bf(y - bf2f(h));
            if (j & 1) { hw[j >> 1] |= ((unsigned)h) << 16; lw[j >> 1] |= ((unsigned)lo) << 16; }
            else       { hw[j >> 1] = (unsigned)h;          lw[j >> 1] = (unsigned)lo; }
            if (MODE == 0) bits |= ((unsigned int)(y > 0.f)) << j;
        }
        uint4 vh; vh.x = hw[0]; vh.y = hw[1]; vh.z = hw[2]; vh.w = hw[3];
        uint4 vl; vl.x = lw[0]; vl.y = lw[1]; vl.z = lw[2]; vl.w = lw[3];
        *(uint4*)&a1h[n][cgi * 8] = vh;
        *(uint4*)&a1l[n][cgi * 8] = vl;
        if (MODE == 0) atomicOr(&m1w[cgi >> 2][n], bits << ((cgi & 3) * 8));
    }
    __syncthreads();

    if (MODE == 0 && q == 0 && tx < 128) {
        m1b[b * N_ + n0 + tx] =
            (unsigned long long)m1w[0][tx] | ((unsigned long long)m1w[1][tx] << 32);
    }

    // running max/argmax for layer3 output (per lane: o = w*16+lhi*4+r)
    float bv0 = -3.4e38f, bv1 = -3.4e38f, bv2 = -3.4e38f, bv3 = -3.4e38f;
    int   bi0 = 0, bi1 = 0, bi2 = 0, bi3 = 0;
    float scr[4], ofr[4];
    #pragma unroll
    for (int r = 0; r < 4; ++r) {
        scr[r] = sSc[w * 16 + lhi * 4 + r];
        ofr[r] = sOff[w * 16 + lhi * 4 + r];
    }

    // ---- two 64-n halves: layer2 -> sB -> layer3(+max), reuse sB
    for (int half = 0; half < 2; ++half) {
        // layer2 MFMA: 16 waves x 2 tasks: og = w&7, nf_l = (w>>3)*2 + ti
        {
            int og = w & 7;
            #pragma unroll
            for (int ti = 0; ti < 2; ++ti) {
                int nf_l = (w >> 3) * 2 + ti;        // 0..3
                int n_l = nf_l * 16 + l15;           // row in sB
                int n_g = half * 64 + n_l;           // row in a1
                f32x4 acc2 = (f32x4){0.f, 0.f, 0.f, 0.f};
                #pragma unroll
                for (int ks = 0; ks < 2; ++ks) {
                    int k0 = ks * 32;
                    int aoff = (og * 16 + l15) * C1_ + k0 + lhi * 8;
                    bf16x8 ah2 = *(const bf16x8*)(w2h + aoff);
                    bf16x8 al2 = *(const bf16x8*)(w2l + aoff);
                    bf16x8 bh2 = *(const bf16x8*)&a1h[n_g][k0 + lhi * 8];
                    bf16x8 bl2 = *(const bf16x8*)&a1l[n_g][k0 + lhi * 8];
                    acc2 = __builtin_amdgcn_mfma_f32_16x16x32_bf16(ah2, bh2, acc2, 0, 0, 0);
                    acc2 = __builtin_amdgcn_mfma_f32_16x16x32_bf16(ah2, bl2, acc2, 0, 0, 0);
                    acc2 = __builtin_amdgcn_mfma_f32_16x16x32_bf16(al2, bh2, acc2, 0, 0, 0);
                }
                unsigned short h4[4], l4[4];
                #pragma unroll
                for (int r = 0; r < 4; ++r) {
                    int o = og * 16 + lhi * 4 + r;
                    float y = fmaxf(acc2[r] + sOff2[o], 0.f);
                    unsigned short h = f2bf(y);
                    h4[r] = h;
                    l4[r] = f2bf(y - bf2f(h));
                    if (MODE == 0 && y > 0.f) atomicOr(&m2w[o >> 5][n_g], 1u << (o & 31));
                }
                uint2 vh; vh.x = pk2(h4[0], h4[1]); vh.y = pk2(h4[2], h4[3]);
                uint2 vl; vl.x = pk2(l4[0], l4[1]); vl.y = pk2(l4[2], l4[3]);
                *(uint2*)&sB[0][n_l][og * 16 + lhi * 4] = vh;
                *(uint2*)&sB[1][n_l][og * 16 + lhi * 4] = vl;
            }
        }
        __syncthreads();

        // layer3 MFMA + immediate BN/ReLU/max: wave w -> 16 o, nf_l 0..3
        #pragma unroll
        for (int nf_l = 0; nf_l < 4; ++nf_l) {
            int n_l = nf_l * 16 + l15;
            f32x4 acc = (f32x4){0.f, 0.f, 0.f, 0.f};
            #pragma unroll
            for (int ks = 0; ks < 4; ++ks) {
                int k0 = ks * 32;
                int orow = q * 256 + w * 16 + l15;
                int off = orow * C2_ + k0 + lhi * 8;
                bf16x8 ah = *(const bf16x8*)(w3hi + off);
                bf16x8 al = *(const bf16x8*)(w3lo + off);
                bf16x8 bh = *(const bf16x8*)&sB[0][n_l][k0 + lhi * 8];
                bf16x8 bl = *(const bf16x8*)&sB[1][n_l][k0 + lhi * 8];
                acc = __builtin_amdgcn_mfma_f32_16x16x32_bf16(ah, bh, acc, 0, 0, 0);
                acc = __builtin_amdgcn_mfma_f32_16x16x32_bf16(ah, bl, acc, 0, 0, 0);
                acc = __builtin_amdgcn_mfma_f32_16x16x32_bf16(al, bh, acc, 0, 0, 0);
            }
            int nn = n0 + half * 64 + nf_l * 16 + l15;
            float y0 = fmaxf(scr[0] * acc[0] + ofr[0], 0.f);
            float y1 = fmaxf(scr[1] * acc[1] + ofr[1], 0.f);
            float y2 = fmaxf(scr[2] * acc[2] + ofr[2], 0.f);
            float y3 = fmaxf(scr[3] * acc[3] + ofr[3], 0.f);
            if (y0 > bv0) { bv0 = y0; bi0 = nn; }    // increasing n: > keeps first
            if (y1 > bv1) { bv1 = y1; bi1 = nn; }
            if (y2 > bv2) { bv2 = y2; bi2 = nn; }
            if (y3 > bv3) { bv3 = y3; bi3 = nn; }
        }
        __syncthreads();   // before next half overwrites sB
    }

    if (MODE == 0 && q == 0 && tx < 128) {
        uint4 mv; mv.x = m2w[0][tx]; mv.y = m2w[1][tx]; mv.z = m2w[2][tx]; mv.w = m2w[3][tx];
        *(uint4*)&m2q[(b * N_ + n0 + tx) * 4] = mv;
    }

    // ---- epilogue: cross-lane (l15 groups) max reduce -> pmL -> 2KB store
    {
        float bv[4] = {bv0, bv1, bv2, bv3};
        int   bi[4] = {bi0, bi1, bi2, bi3};
        #pragma unroll
        for (int r = 0; r < 4; ++r) {
            #pragma unroll
            for (int m = 1; m <= 8; m <<= 1) {
                float ov = __shfl_xor(bv[r], m);
                int oi = __shfl_xor(bi[r], m);
                if (ov > bv[r] || (ov == bv[r] && oi < bi[r])) { bv[r] = ov; bi[r] = oi; }
            }
            if (l15 == 0) {
                pmL[w * 16 + lhi * 4 + r] =
                    ((unsigned long long)__float_as_uint(bv[r]) << 32)
                    | (unsigned int)(~(unsigned int)bi[r]);
            }
        }
    }
    __syncthreads();
    if (tx < 256)
        part[(size_t)slab * (B_ * K_) + b * K_ + q * 256 + tx] = pmL[tx];
}

// Reduce 8 slab partials -> pm[b][o] (prologue only, feeds k_jac).
__global__ __launch_bounds__(256)
void k_reduce(const unsigned long long* __restrict__ part,
              unsigned long long* __restrict__ pm) {
    int gid = blockIdx.x * 256 + threadIdx.x;
    unsigned long long m = part[gid];
    #pragma unroll
    for (int s = 1; s < 8; ++s) {
        unsigned long long v = part[(size_t)s * (B_ * K_) + gid];
        m = (v > m) ? v : m;
    }
    pm[gid] = m;
}

// Fused reduce + r->out + dx + conv + expmap-g-update. 8 blocks (1/batch).
__global__ __launch_bounds__(256)
void k_rdx(const unsigned long long* __restrict__ part,
           const float* __restrict__ f0, const float* __restrict__ pinvT,
           float* __restrict__ out, float* __restrict__ g,
           float* __restrict__ dxg, float* __restrict__ nrmg,
           unsigned int* __restrict__ cnt) {
    __shared__ float redB[4][6];
    __shared__ int isLast;
    int bb = blockIdx.x;           // batch
    int tx = threadIdx.x;          // 256
    int w = tx >> 6;
    int l = tx & 63;

    float acc[6] = {0.f, 0.f, 0.f, 0.f, 0.f, 0.f};
    #pragma unroll
    for (int half = 0; half < 4; ++half) {
        int o = half * 256 + tx;
        unsigned long long m = part[(size_t)bb * K_ + o];
        #pragma unroll
        for (int s = 1; s < 8; ++s) {
            unsigned long long v = part[(size_t)s * (B_ * K_) + bb * K_ + o];
            m = (v > m) ? v : m;
        }
        float fv = __uint_as_float((unsigned int)(m >> 32));
        float rv = fv - f0[bb * K_ + o];
        out[bb * K_ + o] = rv;
        const float4* pp = (const float4*)(pinvT + (size_t)(bb * K_ + o) * 8);
        float4 pa = pp[0], pb = pp[1];
        acc[0] += pa.x * rv; acc[1] += pa.y * rv; acc[2] += pa.z * rv;
        acc[3] += pa.w * rv; acc[4] += pb.x * rv; acc[5] += pb.y * rv;
    }
    #pragma unroll
    for (int i = 0; i < 6; ++i)
        for (int off = 32; off > 0; off >>= 1) acc[i] += __shfl_down(acc[i], off);
    if (l == 0) {
        #pragma unroll
        for (int i = 0; i < 6; ++i) redB[w][i] = acc[i];
    }
    __syncthreads();
    if (tx == 0) {
        float dx6[6];
        #pragma unroll
        for (int i = 0; i < 6; ++i) {
            dx6[i] = redB[0][i] + redB[1][i] + redB[2][i] + redB[3][i];
            atomicExch(&dxg[bb * 6 + i], dx6[i]);
        }
        atomicExch(&nrmg[bb],
                   sqrtf(dx6[0]*dx6[0] + dx6[1]*dx6[1] + dx6[2]*dx6[2]
                       + dx6[3]*dx6[3] + dx6[4]*dx6[4] + dx6[5]*dx6[5]));
    }
    __threadfence();
    __syncthreads();
    if (tx == 0) {
        unsigned int old = atomicAdd(cnt, 1u);
        isLast = (old == B_ - 1) ? 1 : 0;
        if (isLast) atomicExch(cnt, 0u);     // reset for next iteration/replay
    }
    __syncthreads();
    if (!isLast) return;

    // last block: conv check + expmap update of g for all 8 batches
    if (tx < B_) {
        int b = tx;
        float mx = 0.f;
        #pragma unroll
        for (int i = 0; i < B_; ++i) mx = fmaxf(mx, atomicAdd(&nrmg[i], 0.f));
        if (mx < XTOL_) return;
        float d[6];
        #pragma unroll
        for (int i = 0; i < 6; ++i) d[i] = atomicAdd(&dxg[b * 6 + i], 0.f);
        float wx = d[0], wy = d[1], wz = d[2];
        float vx = d[3], vy = d[4], vz = d[5];
        float t2 = wx*wx + wy*wy + wz*wz;
        float t = sqrtf(t2);
        float s1, s2, s3;
        if (t < 1e-4f) {
            s1 = 1.f - t2 / 6.f;
            s2 = 0.5f - t2 / 24.f;
            s3 = 1.f / 6.f - t2 / 120.f;
        } else {
            float st = sinf(t), ct = cosf(t);
            s1 = st / t;
            s2 = (1.f - ct) / t2;
            s3 = (t - st) / (t2 * t);
        }
        float W[3][3] = {{0.f, -wz, wy}, {wz, 0.f, -wx}, {-wy, wx, 0.f}};
        float S[3][3];
        #pragma unroll
        for (int i = 0; i < 3; ++i)
            #pragma unroll
            for (int j = 0; j < 3; ++j)
                S[i][j] = W[i][0]*W[0][j] + W[i][1]*W[1][j] + W[i][2]*W[2][j];
        float R[3][3], V[3][3];
        #pragma unroll
        for (int i = 0; i < 3; ++i)
            #pragma unroll
            for (int j = 0; j < 3; ++j) {
                float id = (i == j) ? 1.f : 0.f;
                R[i][j] = id + s1 * W[i][j] + s2 * S[i][j];
                V[i][j] = id + s2 * W[i][j] + s3 * S[i][j];
            }
        float p[3];
        #pragma unroll
        for (int i = 0; i < 3; ++i) p[i] = V[i][0]*vx + V[i][1]*vy + V[i][2]*vz;
        float* gb = g + b * 16;
        float go[16];
        #pragma unroll
        for (int i = 0; i < 16; ++i) go[i] = gb[i];
        #pragma unroll
        for (int i = 0; i < 3; ++i)
            #pragma unroll
            for (int j = 0; j < 4; ++j)
                gb[i * 4 + j] = R[i][0]*go[0*4+j] + R[i][1]*go[1*4+j]
                              + R[i][2]*go[2*4+j] + p[i]*go[3*4+j];
    }
}

// Analytical Jacobian: one wave per (b,k). lane = layer-1 channel c.
__global__ __launch_bounds__(256)
void k_jac(const float* __restrict__ p0,
           const unsigned long long* __restrict__ m1b,
           const unsigned int* __restrict__ m2q,
           const float* __restrict__ W1, const float* __restrict__ ga1, const float* __restrict__ rv1,
           const float* __restrict__ W2, const float* __restrict__ ga2, const float* __restrict__ rv2,
           const float* __restrict__ W3, const float* __restrict__ ga3, const float* __restrict__ rv3,
           const unsigned long long* __restrict__ pm,
           float* __restrict__ f0, float* __restrict__ J) {
    __shared__ float wvs[4][128];
    int tx = threadIdx.x;
    int wv = tx >> 6;
    int l = tx & 63;
    int w = blockIdx.x * 4 + wv;
    int b = w >> 10;
    int k = w & 1023;

    unsigned long long pk = pm[b * K_ + k];
    float f0v = __uint_as_float((unsigned int)(pk >> 32));
    int ns = (int)(~(unsigned int)pk);
    if (l == 0) f0[b * K_ + k] = f0v;

    unsigned long long m1 = m1b[b * N_ + ns];
    const unsigned int* mq = m2q + (b * N_ + ns) * 4;
    unsigned int qa = mq[0], qb = mq[1], qc = mq[2], qd = mq[3];
    unsigned int blo = (l < 32) ? (qa >> l) : (qb >> (l - 32));
    unsigned int bhi = (l < 32) ? (qc >> l) : (qd >> (l - 32));

    const float* w3r = W3 + k * C2_;
    float s2a = ga2[l] * rsqrtf(rv2[l] + EPS_);
    float s2b = ga2[64 + l] * rsqrtf(rv2[64 + l] + EPS_);
    float wa = (blo & 1u) ? w3r[l] * s2a : 0.f;
    float wb = (bhi & 1u) ? w3r[64 + l] * s2b : 0.f;
    wvs[wv][l] = wa;
    wvs[wv][64 + l] = wb;
    __syncthreads();

    float v = 0.f;
    #pragma unroll 8
    for (int d = 0; d < C2_; ++d) v += wvs[wv][d] * W2[d * C1_ + l];

    float d1l = ((m1 >> l) & 1ull) ? ga1[l] * rsqrtf(rv1[l] + EPS_) : 0.f;
    float vc = v * d1l;
    float fj0 = vc * W1[l * 3 + 0];
    float fj1 = vc * W1[l * 3 + 1];
    float fj2 = vc * W1[l * 3 + 2];
    #pragma unroll
    for (int off = 32; off; off >>= 1) {
        fj0 += __shfl_xor(fj0, off);
        fj1 += __shfl_xor(fj1, off);
        fj2 += __shfl_xor(fj2, off);
    }
    if (l == 0) {
        float D3 = (f0v > 0.f) ? ga3[k] * rsqrtf(rv3[k] + EPS_) : 0.f;
        fj0 *= D3; fj1 *= D3; fj2 *= D3;
        float x = p0[(b * N_ + ns) * 3 + 0];
        float y = p0[(b * N_ + ns) * 3 + 1];
        float z = p0[(b * N_ + ns) * 3 + 2];
        float* Jr = J + (b * K_ + k) * 6;
        Jr[0] = fj1 * (-z) + fj2 * y;
        Jr[1] = fj0 * z    + fj2 * (-x);
        Jr[2] = fj0 * (-y) + fj1 * x;
        Jr[3] = -fj0;
        Jr[4] = -fj1;
        Jr[5] = -fj2;
    }
}

// per-b: H = J^T J, pivotless GJ inverse (SPD), pinvT = (Hinv J^T)^T; g-init.
__global__ void k_hpinv(const float* __restrict__ J, float* __restrict__ pinvT,
                        float* __restrict__ g) {
    int b = blockIdx.x;
    int tx = threadIdx.x;
    __shared__ float red[256][22];
    __shared__ float hinv[36];

    if (tx < 16) g[b * 16 + tx] = (tx % 5 == 0) ? 1.f : 0.f;

    float h[21];
    #pragma unroll
    for (int q = 0; q < 21; ++q) h[q] = 0.f;
    for (int k = tx; k < K_; k += 256) {
        const float* Jr = J + (b * K_ + k) * 6;
        float jv[6] = {Jr[0], Jr[1], Jr[2], Jr[3], Jr[4], Jr[5]};
        int q = 0;
        #pragma unroll
        for (int i = 0; i < 6; ++i)
            #pragma unroll
            for (int jj = i; jj < 6; ++jj) h[q++] += jv[i] * jv[jj];
    }
    #pragma unroll
    for (int q = 0; q < 21; ++q) red[tx][q] = h[q];
    __syncthreads();
    for (int s = 128; s > 0; s >>= 1) {
        if (tx < s)
            for (int q = 0; q < 21; ++q) red[tx][q] += red[tx + s][q];
        __syncthreads();
    }
    if (tx == 0) {
        float A[6][6], Inv[6][6];
        {
            int q = 0;
            #pragma unroll
            for (int i = 0; i < 6; ++i)
                #pragma unroll
                for (int jj = i; jj < 6; ++jj) { A[i][jj] = red[0][q]; A[jj][i] = red[0][q]; ++q; }
        }
        #pragma unroll
        for (int i = 0; i < 6; ++i)
            #pragma unroll
            for (int jj = 0; jj < 6; ++jj) Inv[i][jj] = (i == jj) ? 1.f : 0.f;
        #pragma unroll
        for (int col = 0; col < 6; ++col) {
            float ipv = 1.f / A[col][col];
            #pragma unroll
            for (int jj = 0; jj < 6; ++jj) { A[col][jj] *= ipv; Inv[col][jj] *= ipv; }
            #pragma unroll
            for (int r2 = 0; r2 < 6; ++r2) {
                if (r2 == col) continue;
                float f = A[r2][col];
                #pragma unroll
                for (int jj = 0; jj < 6; ++jj) {
                    A[r2][jj]   -= f * A[col][jj];
                    Inv[r2][jj] -= f * Inv[col][jj];
                }
            }
        }
        #pragma unroll
        for (int i = 0; i < 6; ++i)
            #pragma unroll
            for (int jj = 0; jj < 6; ++jj) hinv[i * 6 + jj] = Inv[i][jj];
    }
    __syncthreads();
    for (int k = tx; k < K_; k += 256) {
        const float* Jr = J + (b * K_ + k) * 6;
        float j0 = Jr[0], j1 = Jr[1], j2 = Jr[2], j3 = Jr[3], j4 = Jr[4], j5 = Jr[5];
        float* pr = pinvT + (b * K_ + k) * 8;
        #pragma unroll
        for (int i = 0; i < 6; ++i) {
            pr[i] = hinv[i * 6 + 0] * j0 + hinv[i * 6 + 1] * j1 + hinv[i * 6 + 2] * j2
                  + hinv[i * 6 + 3] * j3 + hinv[i * 6 + 4] * j4 + hinv[i * 6 + 5] * j5;
        }
        pr[6] = 0.f; pr[7] = 0.f;
    }
}

extern "C" void kernel_launch(void* const* d_in, const int* in_sizes, int n_in,
                              void* d_out, int out_size, void* d_ws, size_t ws_size,
                              hipStream_t stream) {
    const float* p0  = (const float*)d_in[0];
    const float* p1  = (const float*)d_in[1];
    const float* W1  = (const float*)d_in[2];
    const float* b1  = (const float*)d_in[3];
    const float* ga1 = (const float*)d_in[4];
    const float* be1 = (const float*)d_in[5];
    const float* rm1 = (const float*)d_in[6];
    const float* rv1 = (const float*)d_in[7];
    const float* W2  = (const float*)d_in[8];
    const float* b2  = (const float*)d_in[9];
    const float* ga2 = (const float*)d_in[10];
    const float* be2 = (const float*)d_in[11];
    const float* rm2 = (const float*)d_in[12];
    const float* rv2 = (const float*)d_in[13];
    const float* W3  = (const float*)d_in[14];
    const float* b3  = (const float*)d_in[15];
    const float* ga3 = (const float*)d_in[16];
    const float* be3 = (const float*)d_in[17];
    const float* rm3 = (const float*)d_in[18];
    const float* rv3 = (const float*)d_in[19];
    // d_in[20] = maxiter (fixed at 10 in setup)

    float* ws   = (float*)d_ws;
    float* g    = ws + OFF_G;
    float* f0   = ws + OFF_F0;
    unsigned long long* pm  = (unsigned long long*)(ws + OFF_PM);
    unsigned long long* m1b = (unsigned long long*)(ws + OFF_M1);
    unsigned int*       m2q = (unsigned int*)(ws + OFF_M2);
    float* sc3  = ws + OFF_SC3;
    float* off3 = ws + OFF_OFF3;
    float* off2 = ws + OFF_OFF2;
    float* w1f  = ws + OFF_W1F;
    unsigned short* w3hi = (unsigned short*)(ws + OFF_W3HI);
    unsigned short* w3lo = (unsigned short*)(ws + OFF_W3LO);
    unsigned short* w2h  = (unsigned short*)(ws + OFF_W2H);
    unsigned short* w2l  = (unsigned short*)(ws + OFF_W2L);
    float* Jb    = ws + OFF_J;
    float* pinvT = ws + OFF_PINVT;
    unsigned long long* part = (unsigned long long*)(ws + OFF_PART);
    float* dxg   = ws + OFF_DXG;
    float* nrmg  = ws + OFF_NRM;
    unsigned int* cnt = (unsigned int*)(ws + OFF_CNT);
    float* out   = (float*)d_out;

    dim3 gridF(8, B_, 4);   // 8 slabs x 8 batches x 4 o-quarters = 256 blocks

    k_prep<<<(K_ * C2_ + 255) / 256, 256, 0, stream>>>(
        W3, b3, ga3, be3, rm3, rv3,
        W1, b1, ga1, be1, rm1, rv1,
        W2, b2, ga2, be2, rm2, rv2,
        w3hi, w3lo, sc3, off3, w2h, w2l, off2, w1f, cnt);

    // f0 phase (g = I)
    k_fused<0><<<gridF, 1024, 0, stream>>>(p0, g, w1f, w2h, w2l, off2, w3hi, w3lo,
                                           sc3, off3, part, m1b, m2q);
    k_reduce<<<B_ * K_ / 256, 256, 0, stream>>>(part, pm);
    k_jac<<<B_ * K_ / 4, 256, 0, stream>>>(p0, m1b, m2q, W1, ga1, rv1, W2, ga2, rv2,
                                           W3, ga3, rv3, pm, f0, Jb);
    k_hpinv<<<B_, 256, 0, stream>>>(Jb, pinvT, g);

    for (int it = 0; it < 10; ++it) {
        k_fused<1><<<gridF, 1024, 0, stream>>>(p1, g, w1f, w2h, w2l, off2, w3hi, w3lo,
                                               sc3, off3, part, m1b, m2q);
        k_rdx<<<B_, 256, 0, stream>>>(part, f0, pinvT, out, g, dxg, nrmg, cnt);
    }
}

// Round 19
// 255.911 us; speedup vs baseline: 1.5938x; 1.5938x over previous
//
#include <hip/hip_runtime.h>

#define B_ 8
#define N_ 1024
#define C1_ 64
#define C2_ 128
#define K_ 1024
#define EPS_ 1e-5f
#define XTOL_ 1e-7f

// workspace offsets (in floats)
#define OFF_G      0        // 128
#define OFF_F0     128      // 8192
#define OFF_PM     8320     // u64[8192]
#define OFF_M1     24704    // u64[8192]
#define OFF_M2     41088    // u32[8192*4]
#define OFF_SC3    73856    // 1024
#define OFF_OFF3   74880    // 1024
#define OFF_OFF2   75904    // 128
#define OFF_W1F    76032    // 64*4
#define OFF_W3HI   76288    // 1024*128 ushort
#define OFF_W3LO   141824   // 1024*128 ushort
#define OFF_W2H    207360   // 128*64 ushort
#define OFF_W2L    211456   // 128*64 ushort
#define OFF_J      215552   // 8*1024*6
#define OFF_PINVT  264704   // 8*1024*8
#define OFF_PART   330240   // u64[8*8*1024] = 131072 floats
#define OFF_DXG    461312   // 48
#define OFF_NRM    461360   // 8
#define OFF_CNT    461368   // 1 (uint)
// total 461372 floats = 1.85 MB

typedef __attribute__((ext_vector_type(8))) short bf16x8;
typedef __attribute__((ext_vector_type(4))) float f32x4;

static __device__ inline unsigned short f2bf(float x) {
    unsigned u = __float_as_uint(x);
    unsigned r = (u + 0x7FFFu + ((u >> 16) & 1u)) >> 16;
    return (unsigned short)r;
}
static __device__ inline float bf2f(unsigned short h) {
    return __uint_as_float(((unsigned)h) << 16);
}
static __device__ inline unsigned pk2(unsigned short a, unsigned short b) {
    return (unsigned)a | ((unsigned)b << 16);
}

// One-time: split W3/W2 into bf16 hi/lo planes; fold BN into tables; cnt=0.
__global__ __launch_bounds__(256)
void k_prep(const float* __restrict__ W3, const float* __restrict__ b3,
            const float* __restrict__ ga3, const float* __restrict__ be3,
            const float* __restrict__ rm3, const float* __restrict__ rv3,
            const float* __restrict__ W1, const float* __restrict__ b1,
            const float* __restrict__ ga1, const float* __restrict__ be1,
            const float* __restrict__ rm1, const float* __restrict__ rv1,
            const float* __restrict__ W2, const float* __restrict__ b2,
            const float* __restrict__ ga2, const float* __restrict__ be2,
            const float* __restrict__ rm2, const float* __restrict__ rv2,
            unsigned short* __restrict__ w3hi, unsigned short* __restrict__ w3lo,
            float* __restrict__ sc3, float* __restrict__ off3,
            unsigned short* __restrict__ w2h, unsigned short* __restrict__ w2l,
            float* __restrict__ off2, float* __restrict__ w1f,
            unsigned int* __restrict__ cnt) {
    int gid = blockIdx.x * 256 + threadIdx.x;
    if (gid < K_ * C2_) {
        float w = W3[gid];
        unsigned short h = f2bf(w);
        w3hi[gid] = h;
        w3lo[gid] = f2bf(w - bf2f(h));
    }
    if (gid < K_) {
        float sc = ga3[gid] * rsqrtf(rv3[gid] + EPS_);
        sc3[gid] = sc;
        off3[gid] = sc * (b3[gid] - rm3[gid]) + be3[gid];
    }
    if (gid < C2_ * C1_) {
        int o = gid >> 6, c = gid & 63;
        float sc = ga2[o] * rsqrtf(rv2[o] + EPS_);
        float v = W2[o * C1_ + c] * sc;
        unsigned short h = f2bf(v);
        w2h[o * C1_ + c] = h;
        w2l[o * C1_ + c] = f2bf(v - bf2f(h));
    }
    if (gid < C2_) {
        float sc = ga2[gid] * rsqrtf(rv2[gid] + EPS_);
        off2[gid] = sc * (b2[gid] - rm2[gid]) + be2[gid];
    }
    if (gid < C1_) {
        float sc = ga1[gid] * rsqrtf(rv1[gid] + EPS_);
        w1f[gid * 4 + 0] = W1[gid * 3 + 0] * sc;
        w1f[gid * 4 + 1] = W1[gid * 3 + 1] * sc;
        w1f[gid * 4 + 2] = W1[gid * 3 + 2] * sc;
        w1f[gid * 4 + 3] = sc * (b1[gid] - rm1[gid]) + be1[gid];
    }
    if (gid == 0) *cnt = 0u;
}

// Fused PointNet pass, 1024-thread blocks (16 waves -> 4 waves/SIMD at the
// 1-block/CU LDS footprint). Block = (128-pt slab, batch, 256-o quarter),
// grid 256 = one per CU. VGPR budget generous (launch_bounds(1024,4)):
// registers-for-ILP beats waves-for-TLP here (round-18 lesson).
// MODE 0: q==0 block also emits sign-bitmasks for k_jac.
template<int MODE>
__global__ __launch_bounds__(1024, 4)
void k_fused(const float* __restrict__ pts, const float* __restrict__ g,
             const float* __restrict__ w1f,
             const unsigned short* __restrict__ w2h, const unsigned short* __restrict__ w2l,
             const float* __restrict__ off2,
             const unsigned short* __restrict__ w3hi, const unsigned short* __restrict__ w3lo,
             const float* __restrict__ sc3, const float* __restrict__ off3,
             unsigned long long* __restrict__ part,
             unsigned long long* __restrict__ m1b, unsigned int* __restrict__ m2q) {
    __shared__ __align__(16) unsigned short a1h[128][72];    // rows 144B
    __shared__ __align__(16) unsigned short a1l[128][72];
    __shared__ __align__(16) unsigned short sB[2][128][136]; // rows 272B
    __shared__ float sSc[256], sOff[256], sOff2[C2_];
    __shared__ unsigned int m1w[2][128];
    __shared__ unsigned int m2w[4][128];
    __shared__ unsigned long long pmL[256];

    int slab = blockIdx.x;         // 0..7 (128 pts each)
    int b    = blockIdx.y;         // 0..7
    int q    = blockIdx.z;         // 0..3 (256-o quarter)
    int n0   = slab * 128;
    int tx   = threadIdx.x;        // 0..1023
    int w    = tx >> 6;            // wave 0..15
    int l    = tx & 63;
    int l15  = l & 15;
    int lhi  = l >> 4;

    if (tx < 256) { sSc[tx] = sc3[q * 256 + tx]; sOff[tx] = off3[q * 256 + tx]; }
    if (tx < C2_) sOff2[tx] = off2[tx];
    if (MODE == 0 && tx < 128) {
        m1w[0][tx] = 0u; m1w[1][tx] = 0u;
        m2w[0][tx] = 0u; m2w[1][tx] = 0u; m2w[2][tx] = 0u; m2w[3][tx] = 0u;
    }
    __syncthreads();

    // ---- layer1 (+SE3 in MODE 1): thread (n = tx&127, cg = tx>>7 covers 8 c)
    {
        int n = tx & 127;
        int cgi = tx >> 7;         // 0..7
        const float* pp = pts + (b * N_ + n0 + n) * 3;
        float px = pp[0], py = pp[1], pz = pp[2];
        float q0, q1, q2;
        if (MODE == 1) {
            const float* gb = g + b * 16;
            q0 = fmaf(gb[0], px, fmaf(gb[1], py, fmaf(gb[2],  pz, gb[3])));
            q1 = fmaf(gb[4], px, fmaf(gb[5], py, fmaf(gb[6],  pz, gb[7])));
            q2 = fmaf(gb[8], px, fmaf(gb[9], py, fmaf(gb[10], pz, gb[11])));
        } else {
            q0 = px; q1 = py; q2 = pz;
        }
        unsigned int bits = 0u;
        unsigned hw[4], lw[4];
        #pragma unroll
        for (int j = 0; j < 8; ++j) {
            int c = cgi * 8 + j;
            float4 wf = *(const float4*)(w1f + c * 4);
            float y = fmaxf(fmaf(wf.x, q0, fmaf(wf.y, q1, fmaf(wf.z, q2, wf.w))), 0.f);
            unsigned short h = f2bf(y);
            unsigned short lo = f2bf(y - bf2f(h));
            if (j & 1) { hw[j >> 1] |= ((unsigned)h) << 16; lw[j >> 1] |= ((unsigned)lo) << 16; }
            else       { hw[j >> 1] = (unsigned)h;          lw[j >> 1] = (unsigned)lo; }
            if (MODE == 0) bits |= ((unsigned int)(y > 0.f)) << j;
        }
        uint4 vh; vh.x = hw[0]; vh.y = hw[1]; vh.z = hw[2]; vh.w = hw[3];
        uint4 vl; vl.x = lw[0]; vl.y = lw[1]; vl.z = lw[2]; vl.w = lw[3];
        *(uint4*)&a1h[n][cgi * 8] = vh;
        *(uint4*)&a1l[n][cgi * 8] = vl;
        if (MODE == 0) atomicOr(&m1w[cgi >> 2][n], bits << ((cgi & 3) * 8));
    }
    __syncthreads();

    // ---- layer2 MFMA: wave w -> o2-tile (w&7)*16, nf-half (w>>3)*4..+3, K=64
    {
        int og = w & 7;
        int nh = (w >> 3) * 4;
        f32x4 acc2[4];
        #pragma unroll
        for (int nfi = 0; nfi < 4; ++nfi) acc2[nfi] = (f32x4){0.f, 0.f, 0.f, 0.f};
        #pragma unroll
        for (int ks = 0; ks < 2; ++ks) {
            int k0 = ks * 32;
            int aoff = (og * 16 + l15) * C1_ + k0 + lhi * 8;
            bf16x8 ah2 = *(const bf16x8*)(w2h + aoff);
            bf16x8 al2 = *(const bf16x8*)(w2l + aoff);
            #pragma unroll
            for (int nfi = 0; nfi < 4; ++nfi) {
                int n = (nh + nfi) * 16 + l15;
                bf16x8 bh2 = *(const bf16x8*)&a1h[n][k0 + lhi * 8];
                bf16x8 bl2 = *(const bf16x8*)&a1l[n][k0 + lhi * 8];
                acc2[nfi] = __builtin_amdgcn_mfma_f32_16x16x32_bf16(ah2, bh2, acc2[nfi], 0, 0, 0);
                acc2[nfi] = __builtin_amdgcn_mfma_f32_16x16x32_bf16(ah2, bl2, acc2[nfi], 0, 0, 0);
                acc2[nfi] = __builtin_amdgcn_mfma_f32_16x16x32_bf16(al2, bh2, acc2[nfi], 0, 0, 0);
            }
        }
        #pragma unroll
        for (int nfi = 0; nfi < 4; ++nfi) {
            int n = (nh + nfi) * 16 + l15;
            unsigned short h4[4], l4[4];
            #pragma unroll
            for (int r = 0; r < 4; ++r) {
                int o = og * 16 + lhi * 4 + r;
                float y = fmaxf(acc2[nfi][r] + sOff2[o], 0.f);
                unsigned short h = f2bf(y);
                h4[r] = h;
                l4[r] = f2bf(y - bf2f(h));
                if (MODE == 0 && y > 0.f) atomicOr(&m2w[o >> 5][n], 1u << (o & 31));
            }
            uint2 vh; vh.x = pk2(h4[0], h4[1]); vh.y = pk2(h4[2], h4[3]);
            uint2 vl; vl.x = pk2(l4[0], l4[1]); vl.y = pk2(l4[2], l4[3]);
            *(uint2*)&sB[0][n][og * 16 + lhi * 4] = vh;
            *(uint2*)&sB[1][n][og * 16 + lhi * 4] = vl;
        }
    }
    __syncthreads();

    if (MODE == 0 && q == 0 && tx < 128) {
        m1b[b * N_ + n0 + tx] =
            (unsigned long long)m1w[0][tx] | ((unsigned long long)m1w[1][tx] << 32);
        uint4 mv; mv.x = m2w[0][tx]; mv.y = m2w[1][tx]; mv.z = m2w[2][tx]; mv.w = m2w[3][tx];
        *(uint4*)&m2q[(b * N_ + n0 + tx) * 4] = mv;
    }

    // ---- layer3 MFMA: wave w -> o = q*256 + w*16 (16 o), 128 n in nf-chunks
    f32x4 acc[8];
    #pragma unroll
    for (int nf = 0; nf < 8; ++nf) acc[nf] = (f32x4){0.f, 0.f, 0.f, 0.f};

    #pragma unroll
    for (int ks = 0; ks < 4; ++ks) {
        int k0 = ks * 32;
        int orow = q * 256 + w * 16 + l15;
        int off = orow * C2_ + k0 + lhi * 8;
        bf16x8 ah = *(const bf16x8*)(w3hi + off);
        bf16x8 al = *(const bf16x8*)(w3lo + off);
        #pragma unroll
        for (int nh = 0; nh < 2; ++nh) {        // nf chunks of 4 (reg pressure)
            bf16x8 bh[4], bl[4];
            #pragma unroll
            for (int nfi = 0; nfi < 4; ++nfi) {
                int n = (nh * 4 + nfi) * 16 + l15;
                bh[nfi] = *(const bf16x8*)&sB[0][n][k0 + lhi * 8];
                bl[nfi] = *(const bf16x8*)&sB[1][n][k0 + lhi * 8];
            }
            #pragma unroll
            for (int nfi = 0; nfi < 4; ++nfi) {
                int nf = nh * 4 + nfi;
                acc[nf] = __builtin_amdgcn_mfma_f32_16x16x32_bf16(ah, bh[nfi], acc[nf], 0, 0, 0);
                acc[nf] = __builtin_amdgcn_mfma_f32_16x16x32_bf16(ah, bl[nfi], acc[nf], 0, 0, 0);
                acc[nf] = __builtin_amdgcn_mfma_f32_16x16x32_bf16(al, bh[nfi], acc[nf], 0, 0, 0);
            }
        }
    }

    // ---- epilogue: BN3 + ReLU + max/argmax over 128 n -> pmL -> 2KB store
    #pragma unroll
    for (int r = 0; r < 4; ++r) {
        int o_l = w * 16 + lhi * 4 + r;          // 0..255 within quarter
        float sc = sSc[o_l], of = sOff[o_l];
        float bv = -3.4e38f;
        int bi = 0;
        #pragma unroll
        for (int nf = 0; nf < 8; ++nf) {
            float y = fmaxf(sc * acc[nf][r] + of, 0.f);
            int nn = n0 + nf * 16 + l15;
            if (y > bv) { bv = y; bi = nn; }     // increasing n: strict > keeps first
        }
        #pragma unroll
        for (int m = 1; m <= 8; m <<= 1) {
            float ov = __shfl_xor(bv, m);
            int oi = __shfl_xor(bi, m);
            if (ov > bv || (ov == bv && oi < bi)) { bv = ov; bi = oi; }
        }
        if (l15 == 0) {
            pmL[o_l] = ((unsigned long long)__float_as_uint(bv) << 32)
                     | (unsigned int)(~(unsigned int)bi);
        }
    }
    __syncthreads();
    if (tx < 256)
        part[(size_t)slab * (B_ * K_) + b * K_ + q * 256 + tx] = pmL[tx];
}

// Reduce 8 slab partials -> pm[b][o] (prologue only, feeds k_jac).
__global__ __launch_bounds__(256)
void k_reduce(const unsigned long long* __restrict__ part,
              unsigned long long* __restrict__ pm) {
    int gid = blockIdx.x * 256 + threadIdx.x;
    unsigned long long m = part[gid];
    #pragma unroll
    for (int s = 1; s < 8; ++s) {
        unsigned long long v = part[(size_t)s * (B_ * K_) + gid];
        m = (v > m) ? v : m;
    }
    pm[gid] = m;
}

// Fused reduce + r->out + dx + conv + expmap-g-update. 8 blocks (1/batch).
__global__ __launch_bounds__(256)
void k_rdx(const unsigned long long* __restrict__ part,
           const float* __restrict__ f0, const float* __restrict__ pinvT,
           float* __restrict__ out, float* __restrict__ g,
           float* __restrict__ dxg, float* __restrict__ nrmg,
           unsigned int* __restrict__ cnt) {
    __shared__ float redB[4][6];
    __shared__ int isLast;
    int bb = blockIdx.x;           // batch
    int tx = threadIdx.x;          // 256
    int w = tx >> 6;
    int l = tx & 63;

    float acc[6] = {0.f, 0.f, 0.f, 0.f, 0.f, 0.f};
    #pragma unroll
    for (int half = 0; half < 4; ++half) {
        int o = half * 256 + tx;
        unsigned long long m = part[(size_t)bb * K_ + o];
        #pragma unroll
        for (int s = 1; s < 8; ++s) {
            unsigned long long v = part[(size_t)s * (B_ * K_) + bb * K_ + o];
            m = (v > m) ? v : m;
        }
        float fv = __uint_as_float((unsigned int)(m >> 32));
        float rv = fv - f0[bb * K_ + o];
        out[bb * K_ + o] = rv;
        const float4* pp = (const float4*)(pinvT + (size_t)(bb * K_ + o) * 8);
        float4 pa = pp[0], pb = pp[1];
        acc[0] += pa.x * rv; acc[1] += pa.y * rv; acc[2] += pa.z * rv;
        acc[3] += pa.w * rv; acc[4] += pb.x * rv; acc[5] += pb.y * rv;
    }
    #pragma unroll
    for (int i = 0; i < 6; ++i)
        for (int off = 32; off > 0; off >>= 1) acc[i] += __shfl_down(acc[i], off);
    if (l == 0) {
        #pragma unroll
        for (int i = 0; i < 6; ++i) redB[w][i] = acc[i];
    }
    __syncthreads();
    if (tx == 0) {
        float dx6[6];
        #pragma unroll
        for (int i = 0; i < 6; ++i) {
            dx6[i] = redB[0][i] + redB[1][i] + redB[2][i] + redB[3][i];
            atomicExch(&dxg[bb * 6 + i], dx6[i]);
        }
        atomicExch(&nrmg[bb],
                   sqrtf(dx6[0]*dx6[0] + dx6[1]*dx6[1] + dx6[2]*dx6[2]
                       + dx6[3]*dx6[3] + dx6[4]*dx6[4] + dx6[5]*dx6[5]));
    }
    __threadfence();
    __syncthreads();
    if (tx == 0) {
        unsigned int old = atomicAdd(cnt, 1u);
        isLast = (old == B_ - 1) ? 1 : 0;
        if (isLast) atomicExch(cnt, 0u);     // reset for next iteration/replay
    }
    __syncthreads();
    if (!isLast) return;

    // last block: conv check + expmap update of g for all 8 batches
    if (tx < B_) {
        int b = tx;
        float mx = 0.f;
        #pragma unroll
        for (int i = 0; i < B_; ++i) mx = fmaxf(mx, atomicAdd(&nrmg[i], 0.f));
        if (mx < XTOL_) return;
        float d[6];
        #pragma unroll
        for (int i = 0; i < 6; ++i) d[i] = atomicAdd(&dxg[b * 6 + i], 0.f);
        float wx = d[0], wy = d[1], wz = d[2];
        float vx = d[3], vy = d[4], vz = d[5];
        float t2 = wx*wx + wy*wy + wz*wz;
        float t = sqrtf(t2);
        float s1, s2, s3;
        if (t < 1e-4f) {
            s1 = 1.f - t2 / 6.f;
            s2 = 0.5f - t2 / 24.f;
            s3 = 1.f / 6.f - t2 / 120.f;
        } else {
            float st = sinf(t), ct = cosf(t);
            s1 = st / t;
            s2 = (1.f - ct) / t2;
            s3 = (t - st) / (t2 * t);
        }
        float W[3][3] = {{0.f, -wz, wy}, {wz, 0.f, -wx}, {-wy, wx, 0.f}};
        float S[3][3];
        #pragma unroll
        for (int i = 0; i < 3; ++i)
            #pragma unroll
            for (int j = 0; j < 3; ++j)
                S[i][j] = W[i][0]*W[0][j] + W[i][1]*W[1][j] + W[i][2]*W[2][j];
        float R[3][3], V[3][3];
        #pragma unroll
        for (int i = 0; i < 3; ++i)
            #pragma unroll
            for (int j = 0; j < 3; ++j) {
                float id = (i == j) ? 1.f : 0.f;
                R[i][j] = id + s1 * W[i][j] + s2 * S[i][j];
                V[i][j] = id + s2 * W[i][j] + s3 * S[i][j];
            }
        float p[3];
        #pragma unroll
        for (int i = 0; i < 3; ++i) p[i] = V[i][0]*vx + V[i][1]*vy + V[i][2]*vz;
        float* gb = g + b * 16;
        float go[16];
        #pragma unroll
        for (int i = 0; i < 16; ++i) go[i] = gb[i];
        #pragma unroll
        for (int i = 0; i < 3; ++i)
            #pragma unroll
            for (int j = 0; j < 4; ++j)
                gb[i * 4 + j] = R[i][0]*go[0*4+j] + R[i][1]*go[1*4+j]
                              + R[i][2]*go[2*4+j] + p[i]*go[3*4+j];
    }
}

// Analytical Jacobian: one wave per (b,k). lane = layer-1 channel c.
__global__ __launch_bounds__(256)
void k_jac(const float* __restrict__ p0,
           const unsigned long long* __restrict__ m1b,
           const unsigned int* __restrict__ m2q,
           const float* __restrict__ W1, const float* __restrict__ ga1, const float* __restrict__ rv1,
           const float* __restrict__ W2, const float* __restrict__ ga2, const float* __restrict__ rv2,
           const float* __restrict__ W3, const float* __restrict__ ga3, const float* __restrict__ rv3,
           const unsigned long long* __restrict__ pm,
           float* __restrict__ f0, float* __restrict__ J) {
    __shared__ float wvs[4][128];
    int tx = threadIdx.x;
    int wv = tx >> 6;
    int l = tx & 63;
    int w = blockIdx.x * 4 + wv;
    int b = w >> 10;
    int k = w & 1023;

    unsigned long long pk = pm[b * K_ + k];
    float f0v = __uint_as_float((unsigned int)(pk >> 32));
    int ns = (int)(~(unsigned int)pk);
    if (l == 0) f0[b * K_ + k] = f0v;

    unsigned long long m1 = m1b[b * N_ + ns];
    const unsigned int* mq = m2q + (b * N_ + ns) * 4;
    unsigned int qa = mq[0], qb = mq[1], qc = mq[2], qd = mq[3];
    unsigned int blo = (l < 32) ? (qa >> l) : (qb >> (l - 32));
    unsigned int bhi = (l < 32) ? (qc >> l) : (qd >> (l - 32));

    const float* w3r = W3 + k * C2_;
    float s2a = ga2[l] * rsqrtf(rv2[l] + EPS_);
    float s2b = ga2[64 + l] * rsqrtf(rv2[64 + l] + EPS_);
    float wa = (blo & 1u) ? w3r[l] * s2a : 0.f;
    float wb = (bhi & 1u) ? w3r[64 + l] * s2b : 0.f;
    wvs[wv][l] = wa;
    wvs[wv][64 + l] = wb;
    __syncthreads();

    float v = 0.f;
    #pragma unroll 8
    for (int d = 0; d < C2_; ++d) v += wvs[wv][d] * W2[d * C1_ + l];

    float d1l = ((m1 >> l) & 1ull) ? ga1[l] * rsqrtf(rv1[l] + EPS_) : 0.f;
    float vc = v * d1l;
    float fj0 = vc * W1[l * 3 + 0];
    float fj1 = vc * W1[l * 3 + 1];
    float fj2 = vc * W1[l * 3 + 2];
    #pragma unroll
    for (int off = 32; off; off >>= 1) {
        fj0 += __shfl_xor(fj0, off);
        fj1 += __shfl_xor(fj1, off);
        fj2 += __shfl_xor(fj2, off);
    }
    if (l == 0) {
        float D3 = (f0v > 0.f) ? ga3[k] * rsqrtf(rv3[k] + EPS_) : 0.f;
        fj0 *= D3; fj1 *= D3; fj2 *= D3;
        float x = p0[(b * N_ + ns) * 3 + 0];
        float y = p0[(b * N_ + ns) * 3 + 1];
        float z = p0[(b * N_ + ns) * 3 + 2];
        float* Jr = J + (b * K_ + k) * 6;
        Jr[0] = fj1 * (-z) + fj2 * y;
        Jr[1] = fj0 * z    + fj2 * (-x);
        Jr[2] = fj0 * (-y) + fj1 * x;
        Jr[3] = -fj0;
        Jr[4] = -fj1;
        Jr[5] = -fj2;
    }
}

// per-b: H = J^T J, pivotless GJ inverse (SPD), pinvT = (Hinv J^T)^T; g-init.
__global__ void k_hpinv(const float* __restrict__ J, float* __restrict__ pinvT,
                        float* __restrict__ g) {
    int b = blockIdx.x;
    int tx = threadIdx.x;
    __shared__ float red[256][22];
    __shared__ float hinv[36];

    if (tx < 16) g[b * 16 + tx] = (tx % 5 == 0) ? 1.f : 0.f;

    float h[21];
    #pragma unroll
    for (int q = 0; q < 21; ++q) h[q] = 0.f;
    for (int k = tx; k < K_; k += 256) {
        const float* Jr = J + (b * K_ + k) * 6;
        float jv[6] = {Jr[0], Jr[1], Jr[2], Jr[3], Jr[4], Jr[5]};
        int q = 0;
        #pragma unroll
        for (int i = 0; i < 6; ++i)
            #pragma unroll
            for (int jj = i; jj < 6; ++jj) h[q++] += jv[i] * jv[jj];
    }
    #pragma unroll
    for (int q = 0; q < 21; ++q) red[tx][q] = h[q];
    __syncthreads();
    for (int s = 128; s > 0; s >>= 1) {
        if (tx < s)
            for (int q = 0; q < 21; ++q) red[tx][q] += red[tx + s][q];
        __syncthreads();
    }
    if (tx == 0) {
        float A[6][6], Inv[6][6];
        {
            int q = 0;
            #pragma unroll
            for (int i = 0; i < 6; ++i)
                #pragma unroll
                for (int jj = i; jj < 6; ++jj) { A[i][jj] = red[0][q]; A[jj][i] = red[0][q]; ++q; }
        }
        #pragma unroll
        for (int i = 0; i < 6; ++i)
            #pragma unroll
            for (int jj = 0; jj < 6; ++jj) Inv[i][jj] = (i == jj) ? 1.f : 0.f;
        #pragma unroll
        for (int col = 0; col < 6; ++col) {
            float ipv = 1.f / A[col][col];
            #pragma unroll
            for (int jj = 0; jj < 6; ++jj) { A[col][jj] *= ipv; Inv[col][jj] *= ipv; }
            #pragma unroll
            for (int r2 = 0; r2 < 6; ++r2) {
                if (r2 == col) continue;
                float f = A[r2][col];
                #pragma unroll
                for (int jj = 0; jj < 6; ++jj) {
                    A[r2][jj]   -= f * A[col][jj];
                    Inv[r2][jj] -= f * Inv[col][jj];
                }
            }
        }
        #pragma unroll
        for (int i = 0; i < 6; ++i)
            #pragma unroll
            for (int jj = 0; jj < 6; ++jj) hinv[i * 6 + jj] = Inv[i][jj];
    }
    __syncthreads();
    for (int k = tx; k < K_; k += 256) {
        const float* Jr = J + (b * K_ + k) * 6;
        float j0 = Jr[0], j1 = Jr[1], j2 = Jr[2], j3 = Jr[3], j4 = Jr[4], j5 = Jr[5];
        float* pr = pinvT + (b * K_ + k) * 8;
        #pragma unroll
        for (int i = 0; i < 6; ++i) {
            pr[i] = hinv[i * 6 + 0] * j0 + hinv[i * 6 + 1] * j1 + hinv[i * 6 + 2] * j2
                  + hinv[i * 6 + 3] * j3 + hinv[i * 6 + 4] * j4 + hinv[i * 6 + 5] * j5;
        }
        pr[6] = 0.f; pr[7] = 0.f;
    }
}

extern "C" void kernel_launch(void* const* d_in, const int* in_sizes, int n_in,
                              void* d_out, int out_size, void* d_ws, size_t ws_size,
                              hipStream_t stream) {
    const float* p0  = (const float*)d_in[0];
    const float* p1  = (const float*)d_in[1];
    const float* W1  = (const float*)d_in[2];
    const float* b1  = (const float*)d_in[3];
    const float* ga1 = (const float*)d_in[4];
    const float* be1 = (const float*)d_in[5];
    const float* rm1 = (const float*)d_in[6];
    const float* rv1 = (const float*)d_in[7];
    const float* W2  = (const float*)d_in[8];
    const float* b2  = (const float*)d_in[9];
    const float* ga2 = (const float*)d_in[10];
    const float* be2 = (const float*)d_in[11];
    const float* rm2 = (const float*)d_in[12];
    const float* rv2 = (const float*)d_in[13];
    const float* W3  = (const float*)d_in[14];
    const float* b3  = (const float*)d_in[15];
    const float* ga3 = (const float*)d_in[16];
    const float* be3 = (const float*)d_in[17];
    const float* rm3 = (const float*)d_in[18];
    const float* rv3 = (const float*)d_in[19];
    // d_in[20] = maxiter (fixed at 10 in setup)

    float* ws   = (float*)d_ws;
    float* g    = ws + OFF_G;
    float* f0   = ws + OFF_F0;
    unsigned long long* pm  = (unsigned long long*)(ws + OFF_PM);
    unsigned long long* m1b = (unsigned long long*)(ws + OFF_M1);
    unsigned int*       m2q = (unsigned int*)(ws + OFF_M2);
    float* sc3  = ws + OFF_SC3;
    float* off3 = ws + OFF_OFF3;
    float* off2 = ws + OFF_OFF2;
    float* w1f  = ws + OFF_W1F;
    unsigned short* w3hi = (unsigned short*)(ws + OFF_W3HI);
    unsigned short* w3lo = (unsigned short*)(ws + OFF_W3LO);
    unsigned short* w2h  = (unsigned short*)(ws + OFF_W2H);
    unsigned short* w2l  = (unsigned short*)(ws + OFF_W2L);
    float* Jb    = ws + OFF_J;
    float* pinvT = ws + OFF_PINVT;
    unsigned long long* part = (unsigned long long*)(ws + OFF_PART);
    float* dxg   = ws + OFF_DXG;
    float* nrmg  = ws + OFF_NRM;
    unsigned int* cnt = (unsigned int*)(ws + OFF_CNT);
    float* out   = (float*)d_out;

    dim3 gridF(8, B_, 4);   // 8 slabs x 8 batches x 4 o-quarters = 256 blocks

    k_prep<<<(K_ * C2_ + 255) / 256, 256, 0, stream>>>(
        W3, b3, ga3, be3, rm3, rv3,
        W1, b1, ga1, be1, rm1, rv1,
        W2, b2, ga2, be2, rm2, rv2,
        w3hi, w3lo, sc3, off3, w2h, w2l, off2, w1f, cnt);

    // f0 phase (g = I)
    k_fused<0><<<gridF, 1024, 0, stream>>>(p0, g, w1f, w2h, w2l, off2, w3hi, w3lo,
                                           sc3, off3, part, m1b, m2q);
    k_reduce<<<B_ * K_ / 256, 256, 0, stream>>>(part, pm);
    k_jac<<<B_ * K_ / 4, 256, 0, stream>>>(p0, m1b, m2q, W1, ga1, rv1, W2, ga2, rv2,
                                           W3, ga3, rv3, pm, f0, Jb);
    k_hpinv<<<B_, 256, 0, stream>>>(Jb, pinvT, g);

    for (int it = 0; it < 10; ++it) {
        k_fused<1><<<gridF, 1024, 0, stream>>>(p1, g, w1f, w2h, w2l, off2, w3hi, w3lo,
                                               sc3, off3, part, m1b, m2q);
        k_rdx<<<B_, 256, 0, stream>>>(part, f0, pinvT, out, g, dxg, nrmg, cnt);
    }
}